// Round 2
// 801.427 us; speedup vs baseline: 1.0018x; 1.0018x over previous
//
#include <hip/hip_runtime.h>

// Problem constants (from reference setup_inputs / OUT_H, OUT_W)
#define BATCH  16
#define HIN    384
#define WIN    384
#define CH     64
#define OUTH   224
#define OUTW   224

// 16 output pixels per 256-thread block; 16 lanes (x float4) cover the 64 channels.
#define PIX_PER_BLOCK 16
#define BLOCKS_PER_IMG ((OUTH * OUTW) / PIX_PER_BLOCK)   // 50176/16 = 3136
#define TOTAL_BLOCKS   (BATCH * BLOCKS_PER_IMG)           // 50176
#define NXCD 8
#define BLOCKS_PER_XCD (TOTAL_BLOCKS / NXCD)              // 6272 (exact)

// clang native vector type: required by __builtin_nontemporal_store
// (HIP's float4 is a class and is rejected). Same codegen width: dwordx4.
typedef float f32x4 __attribute__((ext_vector_type(4)));

__global__ __launch_bounds__(256) void bilinear_proj_kernel(
    const float* __restrict__ X,      // (B, HIN, WIN, CH)
    const float* __restrict__ Tm,     // (B, 9)
    float* __restrict__ out)          // (B, OUTH, OUTW, CH)
{
    const int lane       = threadIdx.x & 15;   // channel group: 4 floats each
    const int pixInBlock = threadIdx.x >> 4;

    // XCD-contiguous swizzle: hardware round-robins blockIdx across the 8 XCDs.
    // Map hw slot -> logical block so XCD k owns a contiguous range of 6272
    // logical blocks (= 2 whole images, swept row-major). Vertical input-row
    // reuse (output row oy vs oy+1, 14 blocks apart) then stays inside one
    // XCD's L2 instead of crossing to another XCD.
    const int lb = (blockIdx.x % NXCD) * BLOCKS_PER_XCD + blockIdx.x / NXCD;

    // b derived from logical block only -> block-uniform -> scalar transform loads
    const int b          = lb / BLOCKS_PER_IMG;
    const int blkInImg   = lb % BLOCKS_PER_IMG;
    const int pInImg     = blkInImg * PIX_PER_BLOCK + pixInBlock;
    const int oy         = pInImg / OUTW;
    const int ox         = pInImg % OUTW;

    // regular grid in [-1,1], linspace with N points: step = 2/(N-1)
    const float xc = -1.0f + (float)ox * (2.0f / (float)(OUTW - 1));
    const float yc = -1.0f + (float)oy * (2.0f / (float)(OUTH - 1));

    const float* t = Tm + b * 9;
    const float t0 = t[0], t1 = t[1], t2 = t[2];
    const float t3 = t[3], t4 = t[4], t5 = t[5];
    const float t6 = t[6], t7 = t[7], t8 = t[8];

    const float s0 = t0 * xc + t1 * yc + t2;
    const float s1 = t3 * xc + t4 * yc + t5;
    const float s2 = t6 * xc + t7 * yc + t8;
    const float z  = s2 + 1e-6f;
    float x = s0 / z;
    float y = s1 / z;
    x = 0.5f * (x + 1.0f) * (float)WIN;   // note: scaled by W, not W-1 (matches ref)
    y = 0.5f * (y + 1.0f) * (float)HIN;

    // trunc toward zero (C cast == astype(int32))
    int x0 = (int)x;
    int x1 = x0 + 1;
    int y0 = (int)y;
    int y1 = y0 + 1;
    x0 = min(max(x0, 0), WIN - 1);
    x1 = min(max(x1, 0), WIN - 1);
    y0 = min(max(y0, 0), HIN - 1);
    y1 = min(max(y1, 0), HIN - 1);

    // weights from CLIPPED integer coords vs unclipped float coords (matches ref)
    const float x0f = (float)x0, x1f = (float)x1;
    const float y0f = (float)y0, y1f = (float)y1;
    const float wa = (x1f - x) * (y1f - y);
    const float wb = (x1f - x) * (y - y0f);
    const float wc = (x - x0f) * (y1f - y);
    const float wd = (x - x0f) * (y - y0f);

    const int c = lane * 4;
    const size_t imgBase = (size_t)b * (size_t)(HIN * WIN) * CH;

    const f32x4* pa = (const f32x4*)(X + imgBase + ((size_t)(y0 * WIN + x0)) * CH + c);
    const f32x4* pb = (const f32x4*)(X + imgBase + ((size_t)(y1 * WIN + x0)) * CH + c);
    const f32x4* pc = (const f32x4*)(X + imgBase + ((size_t)(y0 * WIN + x1)) * CH + c);
    const f32x4* pd = (const f32x4*)(X + imgBase + ((size_t)(y1 * WIN + x1)) * CH + c);

    const f32x4 va = *pa;
    const f32x4 vb = *pb;
    const f32x4 vc = *pc;
    const f32x4 vd = *pd;

    f32x4 o = wa * va + wb * vb + wc * vc + wd * vd;

    // Output is written once and never re-read: nontemporal store keeps the
    // 205 MB stream from evicting the input reuse window in L2/L3.
    f32x4* po = (f32x4*)(out + ((size_t)b * (OUTH * OUTW) + (size_t)pInImg) * CH + c);
    __builtin_nontemporal_store(o, po);
}

extern "C" void kernel_launch(void* const* d_in, const int* in_sizes, int n_in,
                              void* d_out, int out_size, void* d_ws, size_t ws_size,
                              hipStream_t stream) {
    const float* X  = (const float*)d_in[0];
    const float* Tm = (const float*)d_in[1];
    float* out      = (float*)d_out;

    const int nblocks = TOTAL_BLOCKS;  // 16 * 3136 = 50176
    bilinear_proj_kernel<<<nblocks, 256, 0, stream>>>(X, Tm, out);
}